// Round 10
// baseline (151.880 us; speedup 1.0000x reference)
//
#include <hip/hip_runtime.h>
#include <math.h>

#define DEP   96
#define HEADS 96
#define BSZ   16
#define DIM   512
#define REL   128
#define RELP  129   // REL + nil

typedef __attribute__((ext_vector_type(8))) _Float16  half8;    // 8 fp16 (4 VGPRs)
typedef __attribute__((ext_vector_type(2))) __fp16    fp16x2;   // cvt_pkrtz return type
typedef __attribute__((ext_vector_type(4))) float     floatx4;

__device__ __forceinline__ unsigned short f2h(float x) {
    union { _Float16 h; unsigned short u; } c;
    c.h = (_Float16)x;                                   // v_cvt_f16_f32 (RNE)
    return c.u;
}
// two f32 -> packed 2xf16 in one v_cvt_pkrtz_f16_f32
__device__ __forceinline__ unsigned pk_f2h(float a, float b) {
    union { fp16x2 h; unsigned u; } c;
    c.h = __builtin_amdgcn_cvt_pkrtz(a, b);
    return c.u;
}
// packed fp16 add / relu (VOP3P)
__device__ __forceinline__ unsigned pk_add_h2(unsigned a, unsigned b) {
    unsigned r; asm("v_pk_add_f16 %0, %1, %2" : "=v"(r) : "v"(a), "v"(b)); return r;
}
__device__ __forceinline__ unsigned pk_max_h2(unsigned a, unsigned b) {
    unsigned r; asm("v_pk_max_f16 %0, %1, %2" : "=v"(r) : "v"(a), "v"(b)); return r;
}

#define PSS 72   // proj LDS row stride (fp16 elems): 144 B, 16B-aligned rows

// ---------------------------------------------------------------------------
// Kernel A: projections via fp16 MFMA (R5 shape — unchanged, measured healthy).
//   z=0: P1[m][n] = outs@Wt[:, :512]^T + bt   (f32 out)
//   z=1: P2H[m][n]= graph@Wt[:, 512:]^T       (fp16 out)
// First 32 blocks also cast Wp -> WpH as a prelude.
// ---------------------------------------------------------------------------
__global__ __launch_bounds__(256) void proj_kernel(
    const float* __restrict__ outs, const float* __restrict__ graph,
    const float* __restrict__ Wt, const float* __restrict__ bt,
    const float* __restrict__ Wp,
    float* __restrict__ P1, unsigned short* __restrict__ P2H,
    unsigned short* __restrict__ WpH)
{
    // ---- Wp f32 -> fp16 prelude: 32 blocks x 256 thr ----
    {
        const int fb = (blockIdx.z * gridDim.y + blockIdx.y) * gridDim.x + blockIdx.x;
        if (fb < 32) {
            const int c = fb * 256 + (int)threadIdx.x;       // 0..8191 chunks of 8
            float4 a = *(const float4*)(Wp + (size_t)c * 8);
            float4 b = *(const float4*)(Wp + (size_t)c * 8 + 4);
            uint4 o;
            o.x = pk_f2h(a.x, a.y); o.y = pk_f2h(a.z, a.w);
            o.z = pk_f2h(b.x, b.y); o.w = pk_f2h(b.z, b.w);
            *(uint4*)(WpH + (size_t)c * 8) = o;
        }
    }

    const int z = blockIdx.z;
    const float* A = z ? graph : outs;
    const int off  = z ? DIM : 0;
    const int row0 = blockIdx.y * 32;
    const int col0 = blockIdx.x * 64;

    __shared__ __align__(16) unsigned short As[32 * PSS];   // [m][k] fp16
    __shared__ __align__(16) unsigned short Ws[64 * PSS];   // [n][k] fp16

    const int tid  = threadIdx.x;
    const int lane = tid & 63;
    const int wv   = tid >> 6;          // 0..3
    const int ln15 = lane & 15;
    const int quad = lane >> 4;
    const int mh   = wv & 1;            // m-half: rows [16*mh, 16*mh+16)
    const int nh   = wv >> 1;           // n-half: cols [32*nh, 32*nh+32)

    floatx4 acc[2];
    acc[0] = (floatx4){0.f,0.f,0.f,0.f};
    acc[1] = (floatx4){0.f,0.f,0.f,0.f};

    for (int kt = 0; kt < DIM; kt += 64) {
        // A: f32 load + packed RTZ cast to fp16 LDS (1 slot/thread)
        {
            const int r  = tid >> 3;            // 0..31
            const int e8 = (tid & 7) * 8;
            const float* p = A + (size_t)(row0 + r) * DIM + kt + e8;
            float4 va = *(const float4*)p;
            float4 vb = *(const float4*)(p + 4);
            uint4 o;
            o.x = pk_f2h(va.x, va.y); o.y = pk_f2h(va.z, va.w);
            o.z = pk_f2h(vb.x, vb.y); o.w = pk_f2h(vb.z, vb.w);
            *(uint4*)&As[r * PSS + e8] = o;
        }
        // Wt: f32 load + cast (2 slots/thread)
        #pragma unroll
        for (int q = 0; q < 2; ++q) {
            const int slot = q*256 + tid;       // 0..511
            const int r  = slot >> 3;           // 0..63
            const int e8 = (slot & 7) * 8;
            const float* p = Wt + (size_t)(col0 + r) * (2*DIM) + off + kt + e8;
            float4 va = *(const float4*)p;
            float4 vb = *(const float4*)(p + 4);
            uint4 o;
            o.x = pk_f2h(va.x, va.y); o.y = pk_f2h(va.z, va.w);
            o.z = pk_f2h(vb.x, vb.y); o.w = pk_f2h(vb.z, vb.w);
            *(uint4*)&Ws[r * PSS + e8] = o;
        }
        __syncthreads();
        #pragma unroll
        for (int ks = 0; ks < 64; ks += 32) {
            half8 af = *(const half8*)&As[(mh*16 + ln15) * PSS + ks + quad*8];
            #pragma unroll
            for (int nt = 0; nt < 2; ++nt) {
                half8 bf8 = *(const half8*)&Ws[(nh*32 + nt*16 + ln15) * PSS + ks + quad*8];
                acc[nt] = __builtin_amdgcn_mfma_f32_16x16x32_f16(af, bf8, acc[nt], 0, 0, 0);
            }
        }
        __syncthreads();
    }

    #pragma unroll
    for (int nt = 0; nt < 2; ++nt) {
        #pragma unroll
        for (int reg = 0; reg < 4; ++reg) {
            const int m = row0 + mh*16 + quad*4 + reg;
            const int n = col0 + nh*32 + nt*16 + ln15;
            float v = acc[nt][reg];
            if (!z) P1[(size_t)m * DIM + n] = v + bt[n];
            else    P2H[(size_t)m * DIM + n] = f2h(v);
        }
    }
}

// ---------------------------------------------------------------------------
// Kernel B: fused pairwise relu + fp16-MFMA GEMM + log_softmax(129).
// R10: M-SPLIT. 3 blocks per (d,b): each does 32 heads x 128 rel.
// Grid (3,1536) = 4608 blocks. Rationale (R0-R9 ledger): per-kt staging
// loads serialize because acc=48 leaves no VGPR headroom for hoisting
// (R2: forcing prefetch spilled instantly). Here acc 48 -> 16 (wave owns
// 16m x 64n), staging 7 -> 5 slots/thread, LDS 24.1 KB -> 6 blocks/CU.
// Same BK=64, same barrier count, same (256,4) bounds (the only config
// that never regressed). ws staged 3x per (d,b) — extra L2 traffic only.
// Softmax per 32-row chunk is self-contained (M-split is the legal split).
// ---------------------------------------------------------------------------
#define HSS 72
#define WSS 72

__global__ __launch_bounds__(256, 4) void fused_kernel(
    const float* __restrict__ P1, const unsigned short* __restrict__ P2H,
    const unsigned short* __restrict__ WpH, const float* __restrict__ bp,
    float* __restrict__ out)
{
    const int m0 = blockIdx.x * 32;     // head chunk: 0/32/64
    const int db = blockIdx.y;          // d*16 + b
    const int b  = db & 15;

    // K-loop: hs[32][72] @0 (4608) | ws[128][72] @4608 (18432) |
    //         drowH[512] @23040 (1024) -> 24064 B
    // epilogue overlay (hs dead): pmx[32][2] @0 | pl[32][2] | lseS[32]
    __shared__ __align__(16) char arena[24064];
    unsigned short* hs    = (unsigned short*)arena;            // [32][72]
    unsigned short* ws    = (unsigned short*)(arena + 4608);   // [128][72]
    unsigned short* drowH = (unsigned short*)(arena + 23040);  // [512]
    float* pmx  = (float*)arena;                               // [32][2]
    float* pl   = pmx + 64;                                    // [32][2]
    float* lseS = pl + 64;                                     // [32]

    const int tid  = threadIdx.x;       // 0..255
    const int lane = tid & 63;
    const int wv   = tid >> 6;          // 0..3
    const int ln15 = lane & 15;
    const int quad = lane >> 4;
    const int mh   = wv & 1;            // row half: [16*mh, 16*mh+16)
    const int nh   = wv >> 1;           // col half: [64*nh, 64*nh+64)
    const int e8   = (tid & 7) * 8;     // k-slot (elems), fixed per thread

    // dep row f32 -> fp16 (one-time)
    {
        float2 v = *(const float2*)(P1 + (size_t)db * DIM + tid*2);
        *(unsigned*)&drowH[tid*2] = pk_f2h(v.x, v.y);
    }
    __syncthreads();

    floatx4 acc[4];                     // wave: 16m x 64n
    #pragma unroll
    for (int j = 0; j < 4; ++j) acc[j] = (floatx4){0.f,0.f,0.f,0.f};

    for (int kt = 0; kt < DIM; kt += 64) {
        uint4 dv = *(const uint4*)&drowH[kt + e8];
        // ---- stage hs[hl][e] = fp16 relu(drow[e] + P2H[m0+hl,b,e]), 32x64 ----
        // exactly 1 slot/thread: hl = tid>>3, e8 = (tid&7)*8
        {
            const int hl = tid >> 3;             // 0..31
            uint4 pv = *(const uint4*)(P2H + ((size_t)(m0 + hl) * BSZ + b) * DIM + kt + e8);
            uint4 o;
            o.x = pk_max_h2(pk_add_h2(pv.x, dv.x), 0u);
            o.y = pk_max_h2(pk_add_h2(pv.y, dv.y), 0u);
            o.z = pk_max_h2(pk_add_h2(pv.z, dv.z), 0u);
            o.w = pk_max_h2(pk_add_h2(pv.w, dv.w), 0u);
            *(uint4*)&hs[hl * HSS + e8] = o;
        }
        // ---- stage ws[r][e] = WpH[r][kt+e], 128x64 (4 slots/thread) ----
        #pragma unroll
        for (int q = 0; q < 4; ++q) {
            const int r = (q*256 + tid) >> 3;    // 0..127
            *(uint4*)&ws[r * WSS + e8] =
                *(const uint4*)(WpH + (size_t)r * DIM + kt + e8);
        }
        __syncthreads();

        #pragma unroll
        for (int ks = 0; ks < 64; ks += 32) {
            half8 af = *(const half8*)&hs[(mh*16 + ln15) * HSS + ks + quad*8];
            half8 bf[4];
            #pragma unroll
            for (int nt = 0; nt < 4; ++nt)
                bf[nt] = *(const half8*)&ws[(nh*64 + nt*16 + ln15) * WSS + ks + quad*8];
            #pragma unroll
            for (int nt = 0; nt < 4; ++nt)
                acc[nt] = __builtin_amdgcn_mfma_f32_16x16x32_f16(af, bf[nt], acc[nt], 0, 0, 0);
        }
        __syncthreads();
    }

    // ---- epilogue phase 1: per-quadrant softmax partials (no nil yet) ----
    float bpv[4];
    #pragma unroll
    for (int nt = 0; nt < 4; ++nt) bpv[nt] = bp[nh*64 + nt*16 + ln15];

    #pragma unroll
    for (int reg = 0; reg < 4; ++reg) {
        const int m = mh*16 + quad*4 + reg;      // 0..31 local row
        float s[4];
        #pragma unroll
        for (int nt = 0; nt < 4; ++nt) s[nt] = acc[nt][reg] + bpv[nt];
        float mx = fmaxf(fmaxf(s[0], s[1]), fmaxf(s[2], s[3]));
        #pragma unroll
        for (int msk = 1; msk < 16; msk <<= 1) mx = fmaxf(mx, __shfl_xor(mx, msk));
        float l = 0.f;
        #pragma unroll
        for (int nt = 0; nt < 4; ++nt) l += __expf(s[nt] - mx);
        #pragma unroll
        for (int msk = 1; msk < 16; msk <<= 1) l += __shfl_xor(l, msk);
        if (ln15 == 0) { pmx[m*2 + nh] = mx; pl[m*2 + nh] = l; }
    }
    __syncthreads();

    // ---- phase 1.5: lse once per row ----
    if (tid < 32) {
        const float mx0 = pmx[tid*2], mx1 = pmx[tid*2 + 1];
        const float MX = fmaxf(fmaxf(mx0, mx1), 0.f);   // nil = 0 in max
        const float L  = pl[tid*2] * __expf(mx0 - MX) + pl[tid*2 + 1] * __expf(mx1 - MX)
                       + __expf(-MX);                    // nil term
        lseS[tid] = MX + __logf(L);
    }
    __syncthreads();

    // ---- phase 2: direct stores ----
    #pragma unroll
    for (int reg = 0; reg < 4; ++reg) {
        const int m = mh*16 + quad*4 + reg;
        const float lse = lseS[m];
        const size_t base = ((size_t)db * HEADS + m0 + m) * RELP;
        #pragma unroll
        for (int nt = 0; nt < 4; ++nt)
            out[base + 1 + nh*64 + nt*16 + ln15] = acc[nt][reg] + bpv[nt] - lse;
        if (nh == 0 && ln15 == 0) out[base] = -lse;
    }
}

extern "C" void kernel_launch(void* const* d_in, const int* in_sizes, int n_in,
                              void* d_out, int out_size, void* d_ws, size_t ws_size,
                              hipStream_t stream) {
    const float* outs  = (const float*)d_in[0];
    const float* graph = (const float*)d_in[1];
    const float* Wt    = (const float*)d_in[2];
    const float* bt    = (const float*)d_in[3];
    const float* Wp    = (const float*)d_in[4];
    const float* bp    = (const float*)d_in[5];
    float* out = (float*)d_out;

    // Workspace: 4,849,664 B (WtH eliminated; Wt cast inline in proj).
    float* P1           = (float*)d_ws;                     // [1536][512] f32   (3 MB)
    unsigned short* P2H = (unsigned short*)(P1 + 786432);   // [1536][512] fp16  (1.5 MB)
    unsigned short* WpH = P2H + 786432;                     // [128][512]  fp16  (128 KB)

    proj_kernel<<<dim3(DIM/64, (DEP*BSZ)/32, 2), 256, 0, stream>>>(
        outs, graph, Wt, bt, Wp, P1, P2H, WpH);
    fused_kernel<<<dim3(3, DEP*BSZ), 256, 0, stream>>>(P1, P2H, WpH, bp, out);
}

// Round 11
// 147.011 us; speedup vs baseline: 1.0331x; 1.0331x over previous
//
#include <hip/hip_runtime.h>
#include <math.h>

#define DEP   96
#define HEADS 96
#define BSZ   16
#define DIM   512
#define REL   128
#define RELP  129   // REL + nil

typedef __attribute__((ext_vector_type(8))) _Float16  half8;    // 8 fp16 (4 VGPRs)
typedef __attribute__((ext_vector_type(2))) __fp16    fp16x2;   // cvt_pkrtz return type
typedef __attribute__((ext_vector_type(4))) float     floatx4;

__device__ __forceinline__ unsigned short f2h(float x) {
    union { _Float16 h; unsigned short u; } c;
    c.h = (_Float16)x;                                   // v_cvt_f16_f32 (RNE)
    return c.u;
}
// two f32 -> packed 2xf16 in one v_cvt_pkrtz_f16_f32
__device__ __forceinline__ unsigned pk_f2h(float a, float b) {
    union { fp16x2 h; unsigned u; } c;
    c.h = __builtin_amdgcn_cvt_pkrtz(a, b);
    return c.u;
}
// packed fp16 add / relu (VOP3P)
__device__ __forceinline__ unsigned pk_add_h2(unsigned a, unsigned b) {
    unsigned r; asm("v_pk_add_f16 %0, %1, %2" : "=v"(r) : "v"(a), "v"(b)); return r;
}
__device__ __forceinline__ unsigned pk_max_h2(unsigned a, unsigned b) {
    unsigned r; asm("v_pk_max_f16 %0, %1, %2" : "=v"(r) : "v"(a), "v"(b)); return r;
}

#define PSS 72   // proj LDS row stride (fp16 elems): 144 B, 16B-aligned rows

// ---------------------------------------------------------------------------
// Kernel A: projections via fp16 MFMA (R5 shape — unchanged, measured healthy).
//   z=0: P1[m][n] = outs@Wt[:, :512]^T + bt   (f32 out)
//   z=1: P2H[m][n]= graph@Wt[:, 512:]^T       (fp16 out)
// Prelude (first 32 blocks): cast Wp -> WpF in MFMA B-FRAGMENT ORDER:
//   chunk c = ((kk*8 + nq)*64 + lane), 16 B each, holding
//   Wp[(nq>>2)*64+(nq&3)*16+(lane&15)][kk*32+((lane>>4)&3)*8 + 0..7]
// so fused's B-fragment load is a lane-linear global_load_dwordx4.
// ---------------------------------------------------------------------------
__global__ __launch_bounds__(256) void proj_kernel(
    const float* __restrict__ outs, const float* __restrict__ graph,
    const float* __restrict__ Wt, const float* __restrict__ bt,
    const float* __restrict__ Wp,
    float* __restrict__ P1, unsigned short* __restrict__ P2H,
    unsigned short* __restrict__ WpF)
{
    // ---- Wp f32 -> fp16 fragment-order prelude: 32 blocks x 256 thr ----
    {
        const int fb = (blockIdx.z * gridDim.y + blockIdx.y) * gridDim.x + blockIdx.x;
        if (fb < 32) {
            const int c    = fb * 256 + (int)threadIdx.x;    // 0..8191 chunks
            const int ln   = c & 63;
            const int nq   = (c >> 6) & 7;                   // nh*4 + nt
            const int kk   = c >> 9;                         // kti*2 + ks, 0..15
            const int row  = (nq >> 2) * 64 + (nq & 3) * 16 + (ln & 15);
            const int col  = kk * 32 + ((ln >> 4) & 3) * 8;
            const float* src = Wp + (size_t)row * DIM + col;
            float4 a = *(const float4*)src;
            float4 b = *(const float4*)(src + 4);
            uint4 o;
            o.x = pk_f2h(a.x, a.y); o.y = pk_f2h(a.z, a.w);
            o.z = pk_f2h(b.x, b.y); o.w = pk_f2h(b.z, b.w);
            *(uint4*)(WpF + (size_t)c * 8) = o;
        }
    }

    const int z = blockIdx.z;
    const float* A = z ? graph : outs;
    const int off  = z ? DIM : 0;
    const int row0 = blockIdx.y * 32;
    const int col0 = blockIdx.x * 64;

    __shared__ __align__(16) unsigned short As[32 * PSS];   // [m][k] fp16
    __shared__ __align__(16) unsigned short Ws[64 * PSS];   // [n][k] fp16

    const int tid  = threadIdx.x;
    const int lane = tid & 63;
    const int wv   = tid >> 6;          // 0..3
    const int ln15 = lane & 15;
    const int quad = lane >> 4;
    const int mh   = wv & 1;            // m-half: rows [16*mh, 16*mh+16)
    const int nh   = wv >> 1;           // n-half: cols [32*nh, 32*nh+32)

    floatx4 acc[2];
    acc[0] = (floatx4){0.f,0.f,0.f,0.f};
    acc[1] = (floatx4){0.f,0.f,0.f,0.f};

    for (int kt = 0; kt < DIM; kt += 64) {
        // A: f32 load + packed RTZ cast to fp16 LDS (1 slot/thread)
        {
            const int r  = tid >> 3;            // 0..31
            const int e8 = (tid & 7) * 8;
            const float* p = A + (size_t)(row0 + r) * DIM + kt + e8;
            float4 va = *(const float4*)p;
            float4 vb = *(const float4*)(p + 4);
            uint4 o;
            o.x = pk_f2h(va.x, va.y); o.y = pk_f2h(va.z, va.w);
            o.z = pk_f2h(vb.x, vb.y); o.w = pk_f2h(vb.z, vb.w);
            *(uint4*)&As[r * PSS + e8] = o;
        }
        // Wt: f32 load + cast (2 slots/thread)
        #pragma unroll
        for (int q = 0; q < 2; ++q) {
            const int slot = q*256 + tid;       // 0..511
            const int r  = slot >> 3;           // 0..63
            const int e8 = (slot & 7) * 8;
            const float* p = Wt + (size_t)(col0 + r) * (2*DIM) + off + kt + e8;
            float4 va = *(const float4*)p;
            float4 vb = *(const float4*)(p + 4);
            uint4 o;
            o.x = pk_f2h(va.x, va.y); o.y = pk_f2h(va.z, va.w);
            o.z = pk_f2h(vb.x, vb.y); o.w = pk_f2h(vb.z, vb.w);
            *(uint4*)&Ws[r * PSS + e8] = o;
        }
        __syncthreads();
        #pragma unroll
        for (int ks = 0; ks < 64; ks += 32) {
            half8 af = *(const half8*)&As[(mh*16 + ln15) * PSS + ks + quad*8];
            #pragma unroll
            for (int nt = 0; nt < 2; ++nt) {
                half8 bf8 = *(const half8*)&Ws[(nh*32 + nt*16 + ln15) * PSS + ks + quad*8];
                acc[nt] = __builtin_amdgcn_mfma_f32_16x16x32_f16(af, bf8, acc[nt], 0, 0, 0);
            }
        }
        __syncthreads();
    }

    #pragma unroll
    for (int nt = 0; nt < 2; ++nt) {
        #pragma unroll
        for (int reg = 0; reg < 4; ++reg) {
            const int m = row0 + mh*16 + quad*4 + reg;
            const int n = col0 + nh*32 + nt*16 + ln15;
            float v = acc[nt][reg];
            if (!z) P1[(size_t)m * DIM + n] = v + bt[n];
            else    P2H[(size_t)m * DIM + n] = f2h(v);
        }
    }
}

// ---------------------------------------------------------------------------
// Kernel B: fused pairwise relu + fp16-MFMA GEMM + log_softmax(129).
// R11: ws PIPELINE DELETED. Wp lives in workspace pre-shuffled into exact
// B-fragment order (WpF), so each wave loads its bf as a lane-linear
// coalesced global_load_dwordx4 from L2 (1 KB/instr) — removing per kt/wave:
// 4 ws stage loads + 4 ds_write_b128 + 8 bf ds_read_b128. The 8 bf loads
// are issued BEFORE the stage barrier (independent of LDS), complete at the
// barrier's vmcnt drain, and are consumed from registers in the MFMA phase
// (not held across the loop back-edge -> no R2-style spill pressure).
// Ledger: R6/R7/R9/R10 proved occupancy is NOT the constraint (52-63% occ
// was slower); per-kt serial work is. This cuts it directly.
// LDS 16.8 KB; launch_bounds stays (256,4) — the only config that never hurt.
// Accumulation order identical to R4 -> bit-identical output.
// ---------------------------------------------------------------------------
#define HSS 72

__global__ __launch_bounds__(256, 4) void fused_kernel(
    const float* __restrict__ P1, const unsigned short* __restrict__ P2H,
    const unsigned short* __restrict__ WpF, const float* __restrict__ bp,
    float* __restrict__ out)
{
    const int db = blockIdx.x;      // d*16 + b
    const int b  = db & 15;

    __shared__ __align__(16) unsigned short hs[96 * HSS];   // h tile [m][k]
    __shared__ __align__(16) unsigned short drowH[DIM];     // dep row fp16
    __shared__ float pmx[96][2];     // softmax partials per (row, col-half)
    __shared__ float pl [96][2];
    __shared__ float lseS[96];       // per-row lse

    const int tid  = threadIdx.x;       // 0..255
    const int lane = tid & 63;
    const int wv   = tid >> 6;          // 0..3
    const int ln15 = lane & 15;
    const int quad = lane >> 4;
    const int mh   = wv & 1;            // row half: [48*mh, 48*mh+48)
    const int nh   = wv >> 1;           // col half: [64*nh, 64*nh+64)
    const int e8   = (tid & 7) * 8;     // k-slot (elems), fixed per thread

    // dep row f32 -> fp16 (one-time)
    {
        float2 v = *(const float2*)(P1 + (size_t)db * DIM + tid*2);
        *(unsigned*)&drowH[tid*2] = pk_f2h(v.x, v.y);
    }
    __syncthreads();

    floatx4 acc[3][4];
    #pragma unroll
    for (int i = 0; i < 3; ++i)
        #pragma unroll
        for (int j = 0; j < 4; ++j) acc[i][j] = (floatx4){0.f,0.f,0.f,0.f};

    for (int kti = 0; kti < 8; ++kti) {
        const int kt = kti * 64;

        // ---- bf: 8 coalesced fragment loads from L2 (issued first) ----
        half8 bf[2][4];
        #pragma unroll
        for (int ks = 0; ks < 2; ++ks)
            #pragma unroll
            for (int nt = 0; nt < 4; ++nt)
                bf[ks][nt] = *(const half8*)(WpF +
                    (size_t)((((kti*2 + ks)*8 + nh*4 + nt)*64 + lane)) * 8);

        // ---- stage hs[h][e] = fp16 relu(drow[e] + P2H[h,b,e]), 96x64 ----
        uint4 dv = *(const uint4*)&drowH[kt + e8];
        #pragma unroll
        for (int q = 0; q < 3; ++q) {
            const int h = (q*256 + tid) >> 3;    // 0..95
            uint4 pv = *(const uint4*)(P2H + ((size_t)h * BSZ + b) * DIM + kt + e8);
            uint4 o;
            o.x = pk_max_h2(pk_add_h2(pv.x, dv.x), 0u);
            o.y = pk_max_h2(pk_add_h2(pv.y, dv.y), 0u);
            o.z = pk_max_h2(pk_add_h2(pv.z, dv.z), 0u);
            o.w = pk_max_h2(pk_add_h2(pv.w, dv.w), 0u);
            *(uint4*)&hs[h * HSS + e8] = o;
        }
        __syncthreads();   // hs visible; bf loads drained into registers

        #pragma unroll
        for (int ks = 0; ks < 2; ++ks) {
            half8 af[3];
            #pragma unroll
            for (int mt = 0; mt < 3; ++mt)
                af[mt] = *(const half8*)&hs[(mh*48 + mt*16 + ln15) * HSS + ks*32 + quad*8];
            #pragma unroll
            for (int nt = 0; nt < 4; ++nt)
                #pragma unroll
                for (int mt = 0; mt < 3; ++mt)
                    acc[mt][nt] = __builtin_amdgcn_mfma_f32_16x16x32_f16(
                        af[mt], bf[ks][nt], acc[mt][nt], 0, 0, 0);
        }
        __syncthreads();   // all reads of hs done before next-kt restage
    }

    // ---- epilogue phase 1: per-quadrant softmax partials (no nil yet) ----
    float bpv[4];
    #pragma unroll
    for (int nt = 0; nt < 4; ++nt) bpv[nt] = bp[nh*64 + nt*16 + ln15];

    #pragma unroll
    for (int mt = 0; mt < 3; ++mt) {
        #pragma unroll
        for (int reg = 0; reg < 4; ++reg) {
            const int m = mh*48 + mt*16 + quad*4 + reg;
            float s[4];
            #pragma unroll
            for (int nt = 0; nt < 4; ++nt) s[nt] = acc[mt][nt][reg] + bpv[nt];
            float mx = fmaxf(fmaxf(s[0], s[1]), fmaxf(s[2], s[3]));
            #pragma unroll
            for (int msk = 1; msk < 16; msk <<= 1) mx = fmaxf(mx, __shfl_xor(mx, msk));
            float l = 0.f;
            #pragma unroll
            for (int nt = 0; nt < 4; ++nt) l += __expf(s[nt] - mx);
            #pragma unroll
            for (int msk = 1; msk < 16; msk <<= 1) l += __shfl_xor(l, msk);
            if (ln15 == 0) { pmx[m][nh] = mx; pl[m][nh] = l; }
        }
    }
    __syncthreads();

    // ---- phase 1.5: lse once per row ----
    if (tid < 96) {
        const float mx0 = pmx[tid][0], mx1 = pmx[tid][1];
        const float MX = fmaxf(fmaxf(mx0, mx1), 0.f);   // nil = 0 in max
        const float L  = pl[tid][0] * __expf(mx0 - MX) + pl[tid][1] * __expf(mx1 - MX)
                       + __expf(-MX);                    // nil term
        lseS[tid] = MX + __logf(L);
    }
    __syncthreads();

    // ---- phase 2: direct stores (staged variant measured neutral in R4) ----
    #pragma unroll
    for (int mt = 0; mt < 3; ++mt) {
        #pragma unroll
        for (int reg = 0; reg < 4; ++reg) {
            const int m = mh*48 + mt*16 + quad*4 + reg;
            const float lse = lseS[m];
            const size_t base = ((size_t)db * HEADS + m) * RELP;
            #pragma unroll
            for (int nt = 0; nt < 4; ++nt)
                out[base + 1 + nh*64 + nt*16 + ln15] = acc[mt][nt][reg] + bpv[nt] - lse;
            if (nh == 0 && ln15 == 0) out[base] = -lse;
        }
    }
}

extern "C" void kernel_launch(void* const* d_in, const int* in_sizes, int n_in,
                              void* d_out, int out_size, void* d_ws, size_t ws_size,
                              hipStream_t stream) {
    const float* outs  = (const float*)d_in[0];
    const float* graph = (const float*)d_in[1];
    const float* Wt    = (const float*)d_in[2];
    const float* bt    = (const float*)d_in[3];
    const float* Wp    = (const float*)d_in[4];
    const float* bp    = (const float*)d_in[5];
    float* out = (float*)d_out;

    // Workspace: 4,849,664 B (WtH eliminated; WpF replaces WpH, same size).
    float* P1           = (float*)d_ws;                     // [1536][512] f32   (3 MB)
    unsigned short* P2H = (unsigned short*)(P1 + 786432);   // [1536][512] fp16  (1.5 MB)
    unsigned short* WpF = P2H + 786432;                     // [8192][8]   fp16  (128 KB)

    proj_kernel<<<dim3(DIM/64, (DEP*BSZ)/32, 2), 256, 0, stream>>>(
        outs, graph, Wt, bt, Wp, P1, P2H, WpF);
    fused_kernel<<<DEP*BSZ, 256, 0, stream>>>(P1, P2H, WpF, bp, out);
}

// Round 12
// 143.166 us; speedup vs baseline: 1.0609x; 1.0269x over previous
//
#include <hip/hip_runtime.h>
#include <math.h>

#define DEP   96
#define HEADS 96
#define BSZ   16
#define DIM   512
#define REL   128
#define RELP  129   // REL + nil

typedef __attribute__((ext_vector_type(8))) _Float16  half8;    // 8 fp16 (4 VGPRs)
typedef __attribute__((ext_vector_type(2))) __fp16    fp16x2;   // cvt_pkrtz return type
typedef __attribute__((ext_vector_type(4))) float     floatx4;

__device__ __forceinline__ unsigned short f2h(float x) {
    union { _Float16 h; unsigned short u; } c;
    c.h = (_Float16)x;                                   // v_cvt_f16_f32 (RNE)
    return c.u;
}
// two f32 -> packed 2xf16 in one v_cvt_pkrtz_f16_f32
__device__ __forceinline__ unsigned pk_f2h(float a, float b) {
    union { fp16x2 h; unsigned u; } c;
    c.h = __builtin_amdgcn_cvt_pkrtz(a, b);
    return c.u;
}
// packed fp16 add / relu (VOP3P)
__device__ __forceinline__ unsigned pk_add_h2(unsigned a, unsigned b) {
    unsigned r; asm("v_pk_add_f16 %0, %1, %2" : "=v"(r) : "v"(a), "v"(b)); return r;
}
__device__ __forceinline__ unsigned pk_max_h2(unsigned a, unsigned b) {
    unsigned r; asm("v_pk_max_f16 %0, %1, %2" : "=v"(r) : "v"(a), "v"(b)); return r;
}

#define PSS 72   // proj LDS row stride (fp16 elems): 144 B, 16B-aligned rows

// ---------------------------------------------------------------------------
// Kernel A: projections via fp16 MFMA (R5 shape — unchanged, measured healthy).
//   z=0: P1[m][n] = outs@Wt[:, :512]^T + bt   (f32 out)
//   z=1: P2H[m][n]= graph@Wt[:, 512:]^T       (fp16 out)
// Prelude (first 32 blocks): cast Wp -> WpF in MFMA B-FRAGMENT ORDER:
//   chunk c = ((kk*8 + nq)*64 + lane), 16 B each, holding
//   Wp[(nq>>2)*64+(nq&3)*16+(lane&15)][kk*32+((lane>>4)&3)*8 + 0..7]
// so fused's B-fragment load is a lane-linear global_load_dwordx4.
// ---------------------------------------------------------------------------
__global__ __launch_bounds__(256) void proj_kernel(
    const float* __restrict__ outs, const float* __restrict__ graph,
    const float* __restrict__ Wt, const float* __restrict__ bt,
    const float* __restrict__ Wp,
    float* __restrict__ P1, unsigned short* __restrict__ P2H,
    unsigned short* __restrict__ WpF)
{
    // ---- Wp f32 -> fp16 fragment-order prelude: 32 blocks x 256 thr ----
    {
        const int fb = (blockIdx.z * gridDim.y + blockIdx.y) * gridDim.x + blockIdx.x;
        if (fb < 32) {
            const int c    = fb * 256 + (int)threadIdx.x;    // 0..8191 chunks
            const int ln   = c & 63;
            const int nq   = (c >> 6) & 7;                   // nh*4 + nt
            const int kk   = c >> 9;                         // kti*2 + ks, 0..15
            const int row  = (nq >> 2) * 64 + (nq & 3) * 16 + (ln & 15);
            const int col  = kk * 32 + ((ln >> 4) & 3) * 8;
            const float* src = Wp + (size_t)row * DIM + col;
            float4 a = *(const float4*)src;
            float4 b = *(const float4*)(src + 4);
            uint4 o;
            o.x = pk_f2h(a.x, a.y); o.y = pk_f2h(a.z, a.w);
            o.z = pk_f2h(b.x, b.y); o.w = pk_f2h(b.z, b.w);
            *(uint4*)(WpF + (size_t)c * 8) = o;
        }
    }

    const int z = blockIdx.z;
    const float* A = z ? graph : outs;
    const int off  = z ? DIM : 0;
    const int row0 = blockIdx.y * 32;
    const int col0 = blockIdx.x * 64;

    __shared__ __align__(16) unsigned short As[32 * PSS];   // [m][k] fp16
    __shared__ __align__(16) unsigned short Ws[64 * PSS];   // [n][k] fp16

    const int tid  = threadIdx.x;
    const int lane = tid & 63;
    const int wv   = tid >> 6;          // 0..3
    const int ln15 = lane & 15;
    const int quad = lane >> 4;
    const int mh   = wv & 1;            // m-half: rows [16*mh, 16*mh+16)
    const int nh   = wv >> 1;           // n-half: cols [32*nh, 32*nh+32)

    floatx4 acc[2];
    acc[0] = (floatx4){0.f,0.f,0.f,0.f};
    acc[1] = (floatx4){0.f,0.f,0.f,0.f};

    for (int kt = 0; kt < DIM; kt += 64) {
        // A: f32 load + packed RTZ cast to fp16 LDS (1 slot/thread)
        {
            const int r  = tid >> 3;            // 0..31
            const int e8 = (tid & 7) * 8;
            const float* p = A + (size_t)(row0 + r) * DIM + kt + e8;
            float4 va = *(const float4*)p;
            float4 vb = *(const float4*)(p + 4);
            uint4 o;
            o.x = pk_f2h(va.x, va.y); o.y = pk_f2h(va.z, va.w);
            o.z = pk_f2h(vb.x, vb.y); o.w = pk_f2h(vb.z, vb.w);
            *(uint4*)&As[r * PSS + e8] = o;
        }
        // Wt: f32 load + cast (2 slots/thread)
        #pragma unroll
        for (int q = 0; q < 2; ++q) {
            const int slot = q*256 + tid;       // 0..511
            const int r  = slot >> 3;           // 0..63
            const int e8 = (slot & 7) * 8;
            const float* p = Wt + (size_t)(col0 + r) * (2*DIM) + off + kt + e8;
            float4 va = *(const float4*)p;
            float4 vb = *(const float4*)(p + 4);
            uint4 o;
            o.x = pk_f2h(va.x, va.y); o.y = pk_f2h(va.z, va.w);
            o.z = pk_f2h(vb.x, vb.y); o.w = pk_f2h(vb.z, vb.w);
            *(uint4*)&Ws[r * PSS + e8] = o;
        }
        __syncthreads();
        #pragma unroll
        for (int ks = 0; ks < 64; ks += 32) {
            half8 af = *(const half8*)&As[(mh*16 + ln15) * PSS + ks + quad*8];
            #pragma unroll
            for (int nt = 0; nt < 2; ++nt) {
                half8 bf8 = *(const half8*)&Ws[(nh*32 + nt*16 + ln15) * PSS + ks + quad*8];
                acc[nt] = __builtin_amdgcn_mfma_f32_16x16x32_f16(af, bf8, acc[nt], 0, 0, 0);
            }
        }
        __syncthreads();
    }

    #pragma unroll
    for (int nt = 0; nt < 2; ++nt) {
        #pragma unroll
        for (int reg = 0; reg < 4; ++reg) {
            const int m = row0 + mh*16 + quad*4 + reg;
            const int n = col0 + nh*32 + nt*16 + ln15;
            float v = acc[nt][reg];
            if (!z) P1[(size_t)m * DIM + n] = v + bt[n];
            else    P2H[(size_t)m * DIM + n] = f2h(v);
        }
    }
}

// ---------------------------------------------------------------------------
// Kernel B: fused pairwise relu + fp16-MFMA GEMM + log_softmax(129).
// R12: DOUBLE-BUFFERED hs + ONE barrier per K-tile (was 2). The 11-round
// ledger falsified occupancy (R6/R7/R9/R10: 52-63% occ slower), staging
// bandwidth (R3/R11), and the store path (R4) — the untested invariant was
// the 17 phase-alternating full barriers/block. Here stage(kt+1 -> buf^1)
// and MFMA(buf) share ONE phase (compiler interleaves within a phase; it
// only refuses cross-barrier motion), single __syncthreads per kt:
// barriers 17 -> 10. ws stays deleted (R11): bf fragments load lane-linear
// from WpF. Correctness: iter i's writes to buf^1 ordered after iter i-1's
// reads by the end-of-iter barrier; reads of buf after prior writes ditto.
// LDS = 2x13824 (hs) + 1024 (drow) = 28672 B -> 5 blocks/CU; (256,4) kept.
// Accumulation order identical to R4/R11 -> bit-identical output.
// ---------------------------------------------------------------------------
#define HSS 72

__global__ __launch_bounds__(256, 4) void fused_kernel(
    const float* __restrict__ P1, const unsigned short* __restrict__ P2H,
    const unsigned short* __restrict__ WpF, const float* __restrict__ bp,
    float* __restrict__ out)
{
    const int db = blockIdx.x;      // d*16 + b
    const int b  = db & 15;

    // arena: hs buf0 @0 | buf1 @13824 | drowH @27648 -> 28672 B
    // epilogue overlay (buf0 dead after last barrier): pmx/pl/lseS @0
    __shared__ __align__(16) char arena[28672];
    unsigned short* drowH = (unsigned short*)(arena + 27648);  // [512]
    float* pmx  = (float*)arena;                               // [96][2]
    float* pl   = pmx + 192;                                   // [96][2]
    float* lseS = pl + 192;                                    // [96]

    const int tid  = threadIdx.x;       // 0..255
    const int lane = tid & 63;
    const int wv   = tid >> 6;          // 0..3
    const int ln15 = lane & 15;
    const int quad = lane >> 4;
    const int mh   = wv & 1;            // row half: [48*mh, 48*mh+48)
    const int nh   = wv >> 1;           // col half: [64*nh, 64*nh+64)
    const int e8   = (tid & 7) * 8;     // k-slot (elems), fixed per thread
    const int hrow = tid >> 3;          // staging rows: hrow, hrow+32, hrow+64

    // dep row f32 -> fp16 (one-time)
    {
        float2 v = *(const float2*)(P1 + (size_t)db * DIM + tid*2);
        *(unsigned*)&drowH[tid*2] = pk_f2h(v.x, v.y);
    }
    __syncthreads();

    // prologue: stage tile 0 into buf0
    {
        uint4 dv = *(const uint4*)&drowH[e8];
        unsigned short* hs0 = (unsigned short*)arena;
        #pragma unroll
        for (int q = 0; q < 3; ++q) {
            const int h = q*32 + hrow;
            uint4 pv = *(const uint4*)(P2H + ((size_t)h * BSZ + b) * DIM + e8);
            uint4 o;
            o.x = pk_max_h2(pk_add_h2(pv.x, dv.x), 0u);
            o.y = pk_max_h2(pk_add_h2(pv.y, dv.y), 0u);
            o.z = pk_max_h2(pk_add_h2(pv.z, dv.z), 0u);
            o.w = pk_max_h2(pk_add_h2(pv.w, dv.w), 0u);
            *(uint4*)&hs0[h * HSS + e8] = o;
        }
    }
    __syncthreads();

    floatx4 acc[3][4];
    #pragma unroll
    for (int i = 0; i < 3; ++i)
        #pragma unroll
        for (int j = 0; j < 4; ++j) acc[i][j] = (floatx4){0.f,0.f,0.f,0.f};

    for (int kti = 0; kti < 8; ++kti) {
        unsigned short* hsC = (unsigned short*)(arena + (kti & 1) * 13824);
        unsigned short* hsN = (unsigned short*)(arena + ((kti & 1) ^ 1) * 13824);

        // ---- bf: 8 coalesced fragment loads from L2 (this kt) ----
        half8 bf[2][4];
        #pragma unroll
        for (int ks = 0; ks < 2; ++ks)
            #pragma unroll
            for (int nt = 0; nt < 4; ++nt)
                bf[ks][nt] = *(const half8*)(WpF +
                    (size_t)((((kti*2 + ks)*8 + nh*4 + nt)*64 + lane)) * 8);

        // ---- stage NEXT tile into buf^1 (overlaps MFMA below; no barrier
        //      between them — one phase) ----
        if (kti < 7) {
            const int ktn = (kti + 1) * 64;
            uint4 dv = *(const uint4*)&drowH[ktn + e8];
            #pragma unroll
            for (int q = 0; q < 3; ++q) {
                const int h = q*32 + hrow;
                uint4 pv = *(const uint4*)(P2H + ((size_t)h * BSZ + b) * DIM + ktn + e8);
                uint4 o;
                o.x = pk_max_h2(pk_add_h2(pv.x, dv.x), 0u);
                o.y = pk_max_h2(pk_add_h2(pv.y, dv.y), 0u);
                o.z = pk_max_h2(pk_add_h2(pv.z, dv.z), 0u);
                o.w = pk_max_h2(pk_add_h2(pv.w, dv.w), 0u);
                *(uint4*)&hsN[h * HSS + e8] = o;
            }
        }

        // ---- MFMA on current buffer ----
        #pragma unroll
        for (int ks = 0; ks < 2; ++ks) {
            half8 af[3];
            #pragma unroll
            for (int mt = 0; mt < 3; ++mt)
                af[mt] = *(const half8*)&hsC[(mh*48 + mt*16 + ln15) * HSS + ks*32 + quad*8];
            #pragma unroll
            for (int nt = 0; nt < 4; ++nt)
                #pragma unroll
                for (int mt = 0; mt < 3; ++mt)
                    acc[mt][nt] = __builtin_amdgcn_mfma_f32_16x16x32_f16(
                        af[mt], bf[ks][nt], acc[mt][nt], 0, 0, 0);
        }

        __syncthreads();   // the ONE barrier per kt
    }

    // ---- epilogue phase 1: per-quadrant softmax partials (no nil yet) ----
    float bpv[4];
    #pragma unroll
    for (int nt = 0; nt < 4; ++nt) bpv[nt] = bp[nh*64 + nt*16 + ln15];

    #pragma unroll
    for (int mt = 0; mt < 3; ++mt) {
        #pragma unroll
        for (int reg = 0; reg < 4; ++reg) {
            const int m = mh*48 + mt*16 + quad*4 + reg;
            float s[4];
            #pragma unroll
            for (int nt = 0; nt < 4; ++nt) s[nt] = acc[mt][nt][reg] + bpv[nt];
            float mx = fmaxf(fmaxf(s[0], s[1]), fmaxf(s[2], s[3]));
            #pragma unroll
            for (int msk = 1; msk < 16; msk <<= 1) mx = fmaxf(mx, __shfl_xor(mx, msk));
            float l = 0.f;
            #pragma unroll
            for (int nt = 0; nt < 4; ++nt) l += __expf(s[nt] - mx);
            #pragma unroll
            for (int msk = 1; msk < 16; msk <<= 1) l += __shfl_xor(l, msk);
            if (ln15 == 0) { pmx[m*2 + nh] = mx; pl[m*2 + nh] = l; }
        }
    }
    __syncthreads();

    // ---- phase 1.5: lse once per row ----
    if (tid < 96) {
        const float mx0 = pmx[tid*2], mx1 = pmx[tid*2 + 1];
        const float MX = fmaxf(fmaxf(mx0, mx1), 0.f);   // nil = 0 in max
        const float L  = pl[tid*2] * __expf(mx0 - MX) + pl[tid*2 + 1] * __expf(mx1 - MX)
                       + __expf(-MX);                    // nil term
        lseS[tid] = MX + __logf(L);
    }
    __syncthreads();

    // ---- phase 2: direct stores ----
    #pragma unroll
    for (int mt = 0; mt < 3; ++mt) {
        #pragma unroll
        for (int reg = 0; reg < 4; ++reg) {
            const int m = mh*48 + mt*16 + quad*4 + reg;
            const float lse = lseS[m];
            const size_t base = ((size_t)db * HEADS + m) * RELP;
            #pragma unroll
            for (int nt = 0; nt < 4; ++nt)
                out[base + 1 + nh*64 + nt*16 + ln15] = acc[mt][nt][reg] + bpv[nt] - lse;
            if (nh == 0 && ln15 == 0) out[base] = -lse;
        }
    }
}

extern "C" void kernel_launch(void* const* d_in, const int* in_sizes, int n_in,
                              void* d_out, int out_size, void* d_ws, size_t ws_size,
                              hipStream_t stream) {
    const float* outs  = (const float*)d_in[0];
    const float* graph = (const float*)d_in[1];
    const float* Wt    = (const float*)d_in[2];
    const float* bt    = (const float*)d_in[3];
    const float* Wp    = (const float*)d_in[4];
    const float* bp    = (const float*)d_in[5];
    float* out = (float*)d_out;

    // Workspace: 4,849,664 B (WtH eliminated; WpF replaces WpH, same size).
    float* P1           = (float*)d_ws;                     // [1536][512] f32   (3 MB)
    unsigned short* P2H = (unsigned short*)(P1 + 786432);   // [1536][512] fp16  (1.5 MB)
    unsigned short* WpF = P2H + 786432;                     // [8192][8]   fp16  (128 KB)

    proj_kernel<<<dim3(DIM/64, (DEP*BSZ)/32, 2), 256, 0, stream>>>(
        outs, graph, Wt, bt, Wp, P1, P2H, WpF);
    fused_kernel<<<DEP*BSZ, 256, 0, stream>>>(P1, P2H, WpF, bp, out);
}